// Round 1
// baseline (735.449 us; speedup 1.0000x reference)
//
#include <hip/hip_runtime.h>
#include <hip/hip_bf16.h>
#include <math.h>

// MixtralMoE: B=1, S=4096, H=1024, E=8, F=3584, K=2
// inputs (setup_inputs dict order): hidden_states, gate_w, w1, w3, w2  (all fp32)
// output: fp32 [4096, 1024]

#define T_TOK 4096
#define H_DIM 1024
#define E_NUM 8
#define F_DIM 3584

typedef short short8 __attribute__((ext_vector_type(8)));
typedef float f32x4 __attribute__((ext_vector_type(4)));

__device__ __forceinline__ unsigned short f2bf(float f) {
  union { float f; unsigned u; } v; v.f = f;
  unsigned r = v.u + 0x7FFFu + ((v.u >> 16) & 1u);   // RNE
  return (unsigned short)(r >> 16);
}

// ---------------- gating: logits -> softmax -> top2 -> expert lists ----------
__global__ __launch_bounds__(256) void k_gate(const float* __restrict__ x,
    const float* __restrict__ gatew, int* __restrict__ counts,
    int* __restrict__ ids, float* __restrict__ gws) {
  int lane = threadIdx.x & 63;
  int wid  = threadIdx.x >> 6;
  int t = blockIdx.x * 4 + wid;
  const float4* x4 = (const float4*)(x + (size_t)t * H_DIM);
  const float4* g4 = (const float4*)gatew;
  double acc[E_NUM];
#pragma unroll
  for (int e = 0; e < E_NUM; ++e) acc[e] = 0.0;
#pragma unroll
  for (int i = 0; i < 4; ++i) {
    float4 xv = x4[lane * 4 + i];
#pragma unroll
    for (int e = 0; e < E_NUM; ++e) {
      float4 gv = g4[e * 256 + lane * 4 + i];
      acc[e] += (double)xv.x * gv.x + (double)xv.y * gv.y
              + (double)xv.z * gv.z + (double)xv.w * gv.w;
    }
  }
#pragma unroll
  for (int e = 0; e < E_NUM; ++e) {
#pragma unroll
    for (int off = 32; off > 0; off >>= 1)
      acc[e] += __shfl_xor(acc[e], off, 64);
  }
  if (lane == 0) {
    int i0 = 0;
#pragma unroll
    for (int e = 1; e < E_NUM; ++e) if (acc[e] > acc[i0]) i0 = e;       // ties -> lowest idx
    int i1 = (i0 == 0) ? 1 : 0;
#pragma unroll
    for (int e = 0; e < E_NUM; ++e)
      if (e != i0 && e != i1 && acc[e] > acc[i1]) i1 = e;
    double mx = acc[i0];
    double s = 0.0;
#pragma unroll
    for (int e = 0; e < E_NUM; ++e) s += exp(acc[e] - mx);
    float p0 = (float)(exp(acc[i0] - mx) / s);
    float p1 = (float)(exp(acc[i1] - mx) / s);
    int s0 = atomicAdd(&counts[i0], 1);
    ids[i0 * T_TOK + s0] = t * 2;      gws[i0 * T_TOK + s0] = p0;
    int s1 = atomicAdd(&counts[i1], 1);
    ids[i1 * T_TOK + s1] = t * 2 + 1;  gws[i1 * T_TOK + s1] = p1;
  }
}

// ---------------- LDS staging helpers (XOR-swizzled, T2-style) ---------------
// tile: [128 rows][64 cols] bf16, row stride 128 B; byte ^= (row&7)<<4
__device__ __forceinline__ void stage_cvt(unsigned short* lds,
    const float* __restrict__ src, int r, int c) {
  const float4* s4 = (const float4*)src;
  float4 v[4];
#pragma unroll
  for (int i = 0; i < 4; ++i) v[i] = s4[i];
  unsigned u[8];
#pragma unroll
  for (int i = 0; i < 4; ++i) {
    u[2*i]   = (unsigned)f2bf(v[i].x) | ((unsigned)f2bf(v[i].y) << 16);
    u[2*i+1] = (unsigned)f2bf(v[i].z) | ((unsigned)f2bf(v[i].w) << 16);
  }
  int base = r * 128 + c * 2;
  int sw = (r & 7) << 4;
  *(uint4*)((char*)lds + ((base     ) ^ sw)) = make_uint4(u[0], u[1], u[2], u[3]);
  *(uint4*)((char*)lds + ((base + 16) ^ sw)) = make_uint4(u[4], u[5], u[6], u[7]);
}

__device__ __forceinline__ void stage_raw(unsigned short* lds,
    const unsigned short* __restrict__ src, int r, int c) {
  uint4 v0 = ((const uint4*)src)[0];
  uint4 v1 = ((const uint4*)src)[1];
  int base = r * 128 + c * 2;
  int sw = (r & 7) << 4;
  *(uint4*)((char*)lds + ((base     ) ^ sw)) = v0;
  *(uint4*)((char*)lds + ((base + 16) ^ sw)) = v1;
}

__device__ __forceinline__ short8 frag_ld(const unsigned short* lds, int row, int k) {
  int addr = (row * 128 + k * 2) ^ ((row & 7) << 4);
  return *(const short8*)((const char*)lds + addr);
}

// ---------------- FFN up: G = silu(X@w1^T) * (X@w3^T)  (gathered rows) -------
__global__ __launch_bounds__(256) void k_ffn1(const float* __restrict__ x,
    const float* __restrict__ w1, const float* __restrict__ w3,
    const int* __restrict__ counts, const int* __restrict__ ids,
    unsigned short* __restrict__ G) {
  int e = blockIdx.z;
  int count = counts[e];
  int row0 = blockIdx.y * 128;
  if (row0 >= count) return;
  int fcol0 = blockIdx.x * 128;

  __shared__ unsigned short As[128 * 64], B1s[128 * 64], B3s[128 * 64];
  __shared__ int ids_s[128];

  int t = threadIdx.x;
  if (t < 128) ids_s[t] = (row0 + t < count) ? ids[e * T_TOK + row0 + t] : 0;
  __syncthreads();

  const float* w1p = w1 + (size_t)e * F_DIM * H_DIM;
  const float* w3p = w3 + (size_t)e * F_DIM * H_DIM;

  int lane = t & 63, wid = t >> 6;
  int wm = (wid >> 1) * 64, wn = (wid & 1) * 64;
  int fr_row = lane & 15, fr_k = (lane >> 4) * 8;
  int sr = t >> 2, sc = (t & 3) * 16;

  f32x4 acc1[4][4] = {};
  f32x4 acc3[4][4] = {};

  for (int kk = 0; kk < H_DIM; kk += 64) {
#pragma unroll
    for (int p = 0; p < 2; ++p) {
      int r = p * 64 + sr;
      int id = ids_s[r];
      stage_cvt(As,  x   + (size_t)(id >> 1) * H_DIM   + kk + sc, r, sc);
      stage_cvt(B1s, w1p + (size_t)(fcol0 + r) * H_DIM + kk + sc, r, sc);
      stage_cvt(B3s, w3p + (size_t)(fcol0 + r) * H_DIM + kk + sc, r, sc);
    }
    __syncthreads();
#pragma unroll
    for (int ks = 0; ks < 2; ++ks) {
      short8 a[4];
#pragma unroll
      for (int m = 0; m < 4; ++m)
        a[m] = frag_ld(As, wm + m * 16 + fr_row, ks * 32 + fr_k);
#pragma unroll
      for (int n = 0; n < 4; ++n) {
        short8 b1 = frag_ld(B1s, wn + n * 16 + fr_row, ks * 32 + fr_k);
        short8 b3 = frag_ld(B3s, wn + n * 16 + fr_row, ks * 32 + fr_k);
#pragma unroll
        for (int m = 0; m < 4; ++m) {
          acc1[m][n] = __builtin_amdgcn_mfma_f32_16x16x32_bf16(a[m], b1, acc1[m][n], 0, 0, 0);
          acc3[m][n] = __builtin_amdgcn_mfma_f32_16x16x32_bf16(a[m], b3, acc3[m][n], 0, 0, 0);
        }
      }
    }
    __syncthreads();
  }

  int crow = (lane >> 4) * 4, ccol = lane & 15;
#pragma unroll
  for (int m = 0; m < 4; ++m) {
#pragma unroll
    for (int n = 0; n < 4; ++n) {
#pragma unroll
      for (int j = 0; j < 4; ++j) {
        int rl = wm + m * 16 + crow + j;
        if (row0 + rl < count) {
          int id = ids_s[rl];
          int col = fcol0 + wn + n * 16 + ccol;
          float g1 = acc1[m][n][j], g3 = acc3[m][n][j];
          float g = g1 / (1.f + __expf(-g1)) * g3;   // silu(g1)*g3
          G[(size_t)id * F_DIM + col] = f2bf(g);
        }
      }
    }
  }
}

// ---------------- FFN down: out[t] += p * (G_row @ w2^T) ---------------------
__global__ __launch_bounds__(256) void k_ffn2(const unsigned short* __restrict__ G,
    const float* __restrict__ w2, const int* __restrict__ counts,
    const int* __restrict__ ids, const float* __restrict__ gws,
    float* __restrict__ out) {
  int e = blockIdx.z;
  int count = counts[e];
  int row0 = blockIdx.y * 128;
  if (row0 >= count) return;
  int hcol0 = blockIdx.x * 128;

  __shared__ unsigned short As[128 * 64], Bs[128 * 64];
  __shared__ int ids_s[128];
  __shared__ float gw_s[128];

  int t = threadIdx.x;
  if (t < 128) {
    int ok = (row0 + t < count);
    ids_s[t] = ok ? ids[e * T_TOK + row0 + t] : 0;
    gw_s[t]  = ok ? gws[e * T_TOK + row0 + t] : 0.f;
  }
  __syncthreads();

  const float* w2p = w2 + (size_t)e * H_DIM * F_DIM;

  int lane = t & 63, wid = t >> 6;
  int wm = (wid >> 1) * 64, wn = (wid & 1) * 64;
  int fr_row = lane & 15, fr_k = (lane >> 4) * 8;
  int sr = t >> 2, sc = (t & 3) * 16;

  f32x4 acc[4][4] = {};

  for (int kk = 0; kk < F_DIM; kk += 64) {
#pragma unroll
    for (int p = 0; p < 2; ++p) {
      int r = p * 64 + sr;
      stage_raw(As, G + (size_t)ids_s[r] * F_DIM + kk + sc, r, sc);
      stage_cvt(Bs, w2p + (size_t)(hcol0 + r) * F_DIM + kk + sc, r, sc);
    }
    __syncthreads();
#pragma unroll
    for (int ks = 0; ks < 2; ++ks) {
      short8 a[4];
#pragma unroll
      for (int m = 0; m < 4; ++m)
        a[m] = frag_ld(As, wm + m * 16 + fr_row, ks * 32 + fr_k);
#pragma unroll
      for (int n = 0; n < 4; ++n) {
        short8 b = frag_ld(Bs, wn + n * 16 + fr_row, ks * 32 + fr_k);
#pragma unroll
        for (int m = 0; m < 4; ++m)
          acc[m][n] = __builtin_amdgcn_mfma_f32_16x16x32_bf16(a[m], b, acc[m][n], 0, 0, 0);
      }
    }
    __syncthreads();
  }

  int crow = (lane >> 4) * 4, ccol = lane & 15;
#pragma unroll
  for (int m = 0; m < 4; ++m) {
#pragma unroll
    for (int n = 0; n < 4; ++n) {
#pragma unroll
      for (int j = 0; j < 4; ++j) {
        int rl = wm + m * 16 + crow + j;
        if (row0 + rl < count) {
          int tok = ids_s[rl] >> 1;
          float wgt = gw_s[rl];
          atomicAdd(&out[(size_t)tok * H_DIM + hcol0 + wn + n * 16 + ccol],
                    wgt * acc[m][n][j]);
        }
      }
    }
  }
}

// ---------------- launch -----------------------------------------------------
extern "C" void kernel_launch(void* const* d_in, const int* in_sizes, int n_in,
                              void* d_out, int out_size, void* d_ws, size_t ws_size,
                              hipStream_t stream) {
  const float* x     = (const float*)d_in[0];
  const float* gatew = (const float*)d_in[1];
  const float* w1    = (const float*)d_in[2];
  const float* w3    = (const float*)d_in[3];
  const float* w2    = (const float*)d_in[4];
  float* out = (float*)d_out;

  char* ws = (char*)d_ws;
  int*   counts = (int*)ws;                                   // 8 ints
  int*   ids    = (int*)(ws + 1024);                          // [8][4096] packed t*2+rank
  float* gws    = (float*)(ws + 1024 + E_NUM * T_TOK * 4);    // [8][4096]
  unsigned short* G = (unsigned short*)(ws + (1 << 20));      // [8192][F] bf16, idx = t*2+rank

  hipMemsetAsync(counts, 0, E_NUM * sizeof(int), stream);
  hipMemsetAsync(d_out, 0, (size_t)out_size * sizeof(float), stream);

  k_gate<<<dim3(T_TOK / 4), dim3(256), 0, stream>>>(x, gatew, counts, ids, gws);
  k_ffn1<<<dim3(F_DIM / 128, T_TOK / 128, E_NUM), dim3(256), 0, stream>>>(
      x, w1, w3, counts, ids, G);
  k_ffn2<<<dim3(H_DIM / 128, T_TOK / 128, E_NUM), dim3(256), 0, stream>>>(
      G, w2, counts, ids, gws, out);
}

// Round 4
// 627.974 us; speedup vs baseline: 1.1711x; 1.1711x over previous
//
#include <hip/hip_runtime.h>
#include <hip/hip_bf16.h>
#include <math.h>

// MixtralMoE: B=1, S=4096, H=1024, E=8, F=3584, K=2
// inputs: hidden_states, gate_w, w1, w3, w2 (all fp32); output fp32 [4096,1024]

#define T_TOK 4096
#define H_DIM 1024
#define E_NUM 8
#define F_DIM 3584

typedef short short8 __attribute__((ext_vector_type(8)));
typedef float f32x4 __attribute__((ext_vector_type(4)));

__device__ __forceinline__ unsigned short f2bf(float f) {
  union { float f; unsigned u; } v; v.f = f;
  unsigned r = v.u + 0x7FFFu + ((v.u >> 16) & 1u);   // RNE
  return (unsigned short)(r >> 16);
}
__device__ __forceinline__ unsigned pack2(float a, float b) {
  return (unsigned)f2bf(a) | ((unsigned)f2bf(b) << 16);
}

// async global->LDS, 16B/lane. LDS dest is wave-uniform base + lane*16 (HW).
__device__ __forceinline__ void gll16(const void* g, void* l) {
  __builtin_amdgcn_global_load_lds(
      (const __attribute__((address_space(1))) void*)g,
      (__attribute__((address_space(3))) void*)l, 16, 0, 0);
}

// swizzled LDS read: tile [128 rows][64 cols] bf16, byte ^= (row&7)<<4
__device__ __forceinline__ short8 frag_ld(const unsigned short* lds, int row, int k) {
  int addr = (row * 128 + k * 2) ^ ((row & 7) << 4);
  return *(const short8*)((const char*)lds + addr);
}

// ---------------- fp32 -> bf16 bulk convert (8 elems/thread/iter) -----------
__global__ __launch_bounds__(256) void k_cvt(const float* __restrict__ src,
    unsigned short* __restrict__ dst, int n8) {
  int i = blockIdx.x * 256 + threadIdx.x;
  int stride = gridDim.x * 256;
  for (; i < n8; i += stride) {
    const float4* s = (const float4*)src + (size_t)i * 2;
    float4 a = s[0], b = s[1];
    ((uint4*)dst)[i] = make_uint4(pack2(a.x, a.y), pack2(a.z, a.w),
                                  pack2(b.x, b.y), pack2(b.z, b.w));
  }
}

// ---------------- gating + x->bf16 -------------------------------------------
__global__ __launch_bounds__(256) void k_gate(const float* __restrict__ x,
    const float* __restrict__ gatew, int* __restrict__ counts,
    int* __restrict__ ids, float* __restrict__ gws,
    unsigned short* __restrict__ xbf) {
  int lane = threadIdx.x & 63;
  int wid  = threadIdx.x >> 6;
  int t = blockIdx.x * 4 + wid;
  const float4* x4 = (const float4*)(x + (size_t)t * H_DIM);
  const float4* g4 = (const float4*)gatew;
  float4 xv[4];
#pragma unroll
  for (int i = 0; i < 4; ++i) xv[i] = x4[lane * 4 + i];

  if (xbf) {  // fold x fp32->bf16 conversion into the gate pass
    uint4* xr = (uint4*)(xbf + (size_t)t * H_DIM + lane * 16);
    xr[0] = make_uint4(pack2(xv[0].x, xv[0].y), pack2(xv[0].z, xv[0].w),
                       pack2(xv[1].x, xv[1].y), pack2(xv[1].z, xv[1].w));
    xr[1] = make_uint4(pack2(xv[2].x, xv[2].y), pack2(xv[2].z, xv[2].w),
                       pack2(xv[3].x, xv[3].y), pack2(xv[3].z, xv[3].w));
  }

  double acc[E_NUM];
#pragma unroll
  for (int e = 0; e < E_NUM; ++e) acc[e] = 0.0;
#pragma unroll
  for (int i = 0; i < 4; ++i) {
#pragma unroll
    for (int e = 0; e < E_NUM; ++e) {
      float4 gv = g4[e * 256 + lane * 4 + i];
      acc[e] += (double)xv[i].x * gv.x + (double)xv[i].y * gv.y
              + (double)xv[i].z * gv.z + (double)xv[i].w * gv.w;
    }
  }
#pragma unroll
  for (int e = 0; e < E_NUM; ++e) {
#pragma unroll
    for (int off = 32; off > 0; off >>= 1)
      acc[e] += __shfl_xor(acc[e], off, 64);
  }
  if (lane == 0) {
    int i0 = 0;
#pragma unroll
    for (int e = 1; e < E_NUM; ++e) if (acc[e] > acc[i0]) i0 = e;
    int i1 = (i0 == 0) ? 1 : 0;
#pragma unroll
    for (int e = 0; e < E_NUM; ++e)
      if (e != i0 && e != i1 && acc[e] > acc[i1]) i1 = e;
    double mx = acc[i0];
    double s = 0.0;
#pragma unroll
    for (int e = 0; e < E_NUM; ++e) s += exp(acc[e] - mx);
    float p0 = (float)(exp(acc[i0] - mx) / s);
    float p1 = (float)(exp(acc[i1] - mx) / s);
    int s0 = atomicAdd(&counts[i0], 1);
    ids[i0 * T_TOK + s0] = t * 2;      gws[i0 * T_TOK + s0] = p0;
    int s1 = atomicAdd(&counts[i1], 1);
    ids[i1 * T_TOK + s1] = t * 2 + 1;  gws[i1 * T_TOK + s1] = p1;
  }
}

// ============ fast path: bf16 weights + global_load_lds staging ==============
// staging geometry: 256 thr, 4 rounds p; round p wave w lane l covers
// LDS linear byte off = p*4096 + w*1024 + l*16  -> row r = p*32+w*8+l/8, chunk l&7
// source chunk pre-swizzled: (l&7)^(l>>3)  (rule 21: linear dest, swz source)

__global__ __launch_bounds__(256) void k_ffn1_bf(const unsigned short* __restrict__ xbf,
    const unsigned short* __restrict__ w1b, const unsigned short* __restrict__ w3b,
    const int* __restrict__ counts, const int* __restrict__ ids,
    unsigned short* __restrict__ G) {
  int e = blockIdx.z;
  int count = counts[e];
  int row0 = blockIdx.y * 128;
  if (row0 >= count) return;
  int fcol0 = blockIdx.x * 128;

  __shared__ unsigned short As[128 * 64], B1s[128 * 64], B3s[128 * 64];
  __shared__ int ids_s[128];
  int t = threadIdx.x;
  if (t < 128) ids_s[t] = (row0 + t < count) ? ids[e * T_TOK + row0 + t] : 0;
  __syncthreads();

  int lane = t & 63, wid = t >> 6;
  const unsigned short* w1p = w1b + (size_t)e * (F_DIM * H_DIM);
  const unsigned short* w3p = w3b + (size_t)e * (F_DIM * H_DIM);

  int srck = ((lane & 7) ^ (lane >> 3)) * 8;     // element offset in row
  unsigned offA[4], offB[4];
#pragma unroll
  for (int p = 0; p < 4; ++p) {
    int r = p * 32 + wid * 8 + (lane >> 3);
    offA[p] = (unsigned)(ids_s[r] >> 1) * H_DIM + srck;
    offB[p] = (unsigned)(fcol0 + r) * H_DIM + srck;
  }
  unsigned ldst0 = wid * 1024;

  int wm = (wid >> 1) * 64, wn = (wid & 1) * 64;
  int fr_row = lane & 15, fr_k = (lane >> 4) * 8;
  f32x4 acc1[4][4] = {};
  f32x4 acc3[4][4] = {};

  for (int kk = 0; kk < H_DIM; kk += 64) {
#pragma unroll
    for (int p = 0; p < 4; ++p) {
      unsigned d = ldst0 + p * 4096;
      gll16(xbf + offA[p] + kk, (char*)As + d);
      gll16(w1p + offB[p] + kk, (char*)B1s + d);
      gll16(w3p + offB[p] + kk, (char*)B3s + d);
    }
    __syncthreads();
#pragma unroll
    for (int ks = 0; ks < 2; ++ks) {
      short8 a[4];
#pragma unroll
      for (int m = 0; m < 4; ++m)
        a[m] = frag_ld(As, wm + m * 16 + fr_row, ks * 32 + fr_k);
#pragma unroll
      for (int n = 0; n < 4; ++n) {
        short8 b1 = frag_ld(B1s, wn + n * 16 + fr_row, ks * 32 + fr_k);
        short8 b3 = frag_ld(B3s, wn + n * 16 + fr_row, ks * 32 + fr_k);
#pragma unroll
        for (int m = 0; m < 4; ++m) {
          acc1[m][n] = __builtin_amdgcn_mfma_f32_16x16x32_bf16(a[m], b1, acc1[m][n], 0, 0, 0);
          acc3[m][n] = __builtin_amdgcn_mfma_f32_16x16x32_bf16(a[m], b3, acc3[m][n], 0, 0, 0);
        }
      }
    }
    __syncthreads();
  }

  int crow = (lane >> 4) * 4, ccol = lane & 15;
#pragma unroll
  for (int m = 0; m < 4; ++m)
#pragma unroll
    for (int n = 0; n < 4; ++n)
#pragma unroll
      for (int j = 0; j < 4; ++j) {
        int rl = wm + m * 16 + crow + j;
        if (row0 + rl < count) {
          int id = ids_s[rl];
          int col = fcol0 + wn + n * 16 + ccol;
          float g1 = acc1[m][n][j], g3 = acc3[m][n][j];
          float g = g1 / (1.f + __expf(-g1)) * g3;
          G[(size_t)id * F_DIM + col] = f2bf(g);
        }
      }
}

__global__ __launch_bounds__(256) void k_ffn2_bf(const unsigned short* __restrict__ G,
    const unsigned short* __restrict__ w2b, const int* __restrict__ counts,
    const int* __restrict__ ids, const float* __restrict__ gws,
    float* __restrict__ out) {
  int e = blockIdx.z;
  int count = counts[e];
  int row0 = blockIdx.y * 128;
  if (row0 >= count) return;
  int hcol0 = blockIdx.x * 128;

  __shared__ unsigned short As[128 * 64], Bs[128 * 64];
  __shared__ int ids_s[128];
  __shared__ float gw_s[128];
  int t = threadIdx.x;
  if (t < 128) {
    int ok = (row0 + t < count);
    ids_s[t] = ok ? ids[e * T_TOK + row0 + t] : 0;
    gw_s[t]  = ok ? gws[e * T_TOK + row0 + t] : 0.f;
  }
  __syncthreads();

  int lane = t & 63, wid = t >> 6;
  const unsigned short* w2p = w2b + (size_t)e * (H_DIM * F_DIM);

  int srck = ((lane & 7) ^ (lane >> 3)) * 8;
  unsigned offA[4], offB[4];
#pragma unroll
  for (int p = 0; p < 4; ++p) {
    int r = p * 32 + wid * 8 + (lane >> 3);
    offA[p] = (unsigned)ids_s[r] * F_DIM + srck;
    offB[p] = (unsigned)(hcol0 + r) * F_DIM + srck;
  }
  unsigned ldst0 = wid * 1024;

  int wm = (wid >> 1) * 64, wn = (wid & 1) * 64;
  int fr_row = lane & 15, fr_k = (lane >> 4) * 8;
  f32x4 acc[4][4] = {};

  for (int kk = 0; kk < F_DIM; kk += 64) {
#pragma unroll
    for (int p = 0; p < 4; ++p) {
      unsigned d = ldst0 + p * 4096;
      gll16(G   + offA[p] + kk, (char*)As + d);
      gll16(w2p + offB[p] + kk, (char*)Bs + d);
    }
    __syncthreads();
#pragma unroll
    for (int ks = 0; ks < 2; ++ks) {
      short8 a[4];
#pragma unroll
      for (int m = 0; m < 4; ++m)
        a[m] = frag_ld(As, wm + m * 16 + fr_row, ks * 32 + fr_k);
#pragma unroll
      for (int n = 0; n < 4; ++n) {
        short8 b = frag_ld(Bs, wn + n * 16 + fr_row, ks * 32 + fr_k);
#pragma unroll
        for (int m = 0; m < 4; ++m)
          acc[m][n] = __builtin_amdgcn_mfma_f32_16x16x32_bf16(a[m], b, acc[m][n], 0, 0, 0);
      }
    }
    __syncthreads();
  }

  int crow = (lane >> 4) * 4, ccol = lane & 15;
#pragma unroll
  for (int m = 0; m < 4; ++m)
#pragma unroll
    for (int n = 0; n < 4; ++n)
#pragma unroll
      for (int j = 0; j < 4; ++j) {
        int rl = wm + m * 16 + crow + j;
        if (row0 + rl < count) {
          int tok = ids_s[rl] >> 1;
          atomicAdd(&out[(size_t)tok * H_DIM + hcol0 + wn + n * 16 + ccol],
                    gw_s[rl] * acc[m][n][j]);
        }
      }
}

// ============ fallback path (fp32 staging, R1 kernels) =======================
__device__ __forceinline__ void stage_cvt(unsigned short* lds,
    const float* __restrict__ src, int r, int c) {
  const float4* s4 = (const float4*)src;
  float4 v[4];
#pragma unroll
  for (int i = 0; i < 4; ++i) v[i] = s4[i];
  unsigned u[8];
#pragma unroll
  for (int i = 0; i < 4; ++i) {
    u[2*i]   = pack2(v[i].x, v[i].y);
    u[2*i+1] = pack2(v[i].z, v[i].w);
  }
  int base = r * 128 + c * 2;
  int sw = (r & 7) << 4;
  *(uint4*)((char*)lds + ((base     ) ^ sw)) = make_uint4(u[0], u[1], u[2], u[3]);
  *(uint4*)((char*)lds + ((base + 16) ^ sw)) = make_uint4(u[4], u[5], u[6], u[7]);
}
__device__ __forceinline__ void stage_raw(unsigned short* lds,
    const unsigned short* __restrict__ src, int r, int c) {
  uint4 v0 = ((const uint4*)src)[0];
  uint4 v1 = ((const uint4*)src)[1];
  int base = r * 128 + c * 2;
  int sw = (r & 7) << 4;
  *(uint4*)((char*)lds + ((base     ) ^ sw)) = v0;
  *(uint4*)((char*)lds + ((base + 16) ^ sw)) = v1;
}

__global__ __launch_bounds__(256) void k_ffn1_f32(const float* __restrict__ x,
    const float* __restrict__ w1, const float* __restrict__ w3,
    const int* __restrict__ counts, const int* __restrict__ ids,
    unsigned short* __restrict__ G) {
  int e = blockIdx.z;
  int count = counts[e];
  int row0 = blockIdx.y * 128;
  if (row0 >= count) return;
  int fcol0 = blockIdx.x * 128;
  __shared__ unsigned short As[128 * 64], B1s[128 * 64], B3s[128 * 64];
  __shared__ int ids_s[128];
  int t = threadIdx.x;
  if (t < 128) ids_s[t] = (row0 + t < count) ? ids[e * T_TOK + row0 + t] : 0;
  __syncthreads();
  const float* w1p = w1 + (size_t)e * F_DIM * H_DIM;
  const float* w3p = w3 + (size_t)e * F_DIM * H_DIM;
  int lane = t & 63, wid = t >> 6;
  int wm = (wid >> 1) * 64, wn = (wid & 1) * 64;
  int fr_row = lane & 15, fr_k = (lane >> 4) * 8;
  int sr = t >> 2, sc = (t & 3) * 16;
  f32x4 acc1[4][4] = {};
  f32x4 acc3[4][4] = {};
  for (int kk = 0; kk < H_DIM; kk += 64) {
#pragma unroll
    for (int p = 0; p < 2; ++p) {
      int r = p * 64 + sr;
      int id = ids_s[r];
      stage_cvt(As,  x   + (size_t)(id >> 1) * H_DIM   + kk + sc, r, sc);
      stage_cvt(B1s, w1p + (size_t)(fcol0 + r) * H_DIM + kk + sc, r, sc);
      stage_cvt(B3s, w3p + (size_t)(fcol0 + r) * H_DIM + kk + sc, r, sc);
    }
    __syncthreads();
#pragma unroll
    for (int ks = 0; ks < 2; ++ks) {
      short8 a[4];
#pragma unroll
      for (int m = 0; m < 4; ++m)
        a[m] = frag_ld(As, wm + m * 16 + fr_row, ks * 32 + fr_k);
#pragma unroll
      for (int n = 0; n < 4; ++n) {
        short8 b1 = frag_ld(B1s, wn + n * 16 + fr_row, ks * 32 + fr_k);
        short8 b3 = frag_ld(B3s, wn + n * 16 + fr_row, ks * 32 + fr_k);
#pragma unroll
        for (int m = 0; m < 4; ++m) {
          acc1[m][n] = __builtin_amdgcn_mfma_f32_16x16x32_bf16(a[m], b1, acc1[m][n], 0, 0, 0);
          acc3[m][n] = __builtin_amdgcn_mfma_f32_16x16x32_bf16(a[m], b3, acc3[m][n], 0, 0, 0);
        }
      }
    }
    __syncthreads();
  }
  int crow = (lane >> 4) * 4, ccol = lane & 15;
#pragma unroll
  for (int m = 0; m < 4; ++m)
#pragma unroll
    for (int n = 0; n < 4; ++n)
#pragma unroll
      for (int j = 0; j < 4; ++j) {
        int rl = wm + m * 16 + crow + j;
        if (row0 + rl < count) {
          int id = ids_s[rl];
          int col = fcol0 + wn + n * 16 + ccol;
          float g1 = acc1[m][n][j], g3 = acc3[m][n][j];
          float g = g1 / (1.f + __expf(-g1)) * g3;
          G[(size_t)id * F_DIM + col] = f2bf(g);
        }
      }
}

__global__ __launch_bounds__(256) void k_ffn2_f32(const unsigned short* __restrict__ G,
    const float* __restrict__ w2, const int* __restrict__ counts,
    const int* __restrict__ ids, const float* __restrict__ gws,
    float* __restrict__ out) {
  int e = blockIdx.z;
  int count = counts[e];
  int row0 = blockIdx.y * 128;
  if (row0 >= count) return;
  int hcol0 = blockIdx.x * 128;
  __shared__ unsigned short As[128 * 64], Bs[128 * 64];
  __shared__ int ids_s[128];
  __shared__ float gw_s[128];
  int t = threadIdx.x;
  if (t < 128) {
    int ok = (row0 + t < count);
    ids_s[t] = ok ? ids[e * T_TOK + row0 + t] : 0;
    gw_s[t]  = ok ? gws[e * T_TOK + row0 + t] : 0.f;
  }
  __syncthreads();
  const float* w2p = w2 + (size_t)e * H_DIM * F_DIM;
  int lane = t & 63, wid = t >> 6;
  int wm = (wid >> 1) * 64, wn = (wid & 1) * 64;
  int fr_row = lane & 15, fr_k = (lane >> 4) * 8;
  int sr = t >> 2, sc = (t & 3) * 16;
  f32x4 acc[4][4] = {};
  for (int kk = 0; kk < F_DIM; kk += 64) {
#pragma unroll
    for (int p = 0; p < 2; ++p) {
      int r = p * 64 + sr;
      stage_raw(As, G + (size_t)ids_s[r] * F_DIM + kk + sc, r, sc);
      stage_cvt(Bs, w2p + (size_t)(hcol0 + r) * F_DIM + kk + sc, r, sc);
    }
    __syncthreads();
#pragma unroll
    for (int ks = 0; ks < 2; ++ks) {
      short8 a[4];
#pragma unroll
      for (int m = 0; m < 4; ++m)
        a[m] = frag_ld(As, wm + m * 16 + fr_row, ks * 32 + fr_k);
#pragma unroll
      for (int n = 0; n < 4; ++n) {
        short8 b = frag_ld(Bs, wn + n * 16 + fr_row, ks * 32 + fr_k);
#pragma unroll
        for (int m = 0; m < 4; ++m)
          acc[m][n] = __builtin_amdgcn_mfma_f32_16x16x32_bf16(a[m], b, acc[m][n], 0, 0, 0);
      }
    }
    __syncthreads();
  }
  int crow = (lane >> 4) * 4, ccol = lane & 15;
#pragma unroll
  for (int m = 0; m < 4; ++m)
#pragma unroll
    for (int n = 0; n < 4; ++n)
#pragma unroll
      for (int j = 0; j < 4; ++j) {
        int rl = wm + m * 16 + crow + j;
        if (row0 + rl < count) {
          int tok = ids_s[rl] >> 1;
          atomicAdd(&out[(size_t)tok * H_DIM + hcol0 + wn + n * 16 + ccol],
                    gw_s[rl] * acc[m][n][j]);
        }
      }
}

// ---------------- launch -----------------------------------------------------
extern "C" void kernel_launch(void* const* d_in, const int* in_sizes, int n_in,
                              void* d_out, int out_size, void* d_ws, size_t ws_size,
                              hipStream_t stream) {
  const float* x     = (const float*)d_in[0];
  const float* gatew = (const float*)d_in[1];
  const float* w1    = (const float*)d_in[2];
  const float* w3    = (const float*)d_in[3];
  const float* w2    = (const float*)d_in[4];
  float* out = (float*)d_out;

  char* ws = (char*)d_ws;
  int*   counts = (int*)ws;
  int*   ids    = (int*)(ws + 4096);
  float* gws    = (float*)(ws + 4096 + E_NUM * T_TOK * 4);

  const size_t WBYTES = (size_t)E_NUM * F_DIM * H_DIM * 2;  // 58,720,256
  unsigned short* xbf = (unsigned short*)(ws + (1ull << 20));
  unsigned short* w1b = (unsigned short*)(ws + (16ull << 20));
  unsigned short* w3b = (unsigned short*)(ws + (16ull << 20) + WBYTES);
  unsigned short* w2b = (unsigned short*)(ws + (16ull << 20) + 2 * WBYTES);
  unsigned short* Gf  = (unsigned short*)(ws + (16ull << 20) + 3 * WBYTES);
  size_t required = (16ull << 20) + 4 * WBYTES;              // ~252 MB

  hipMemsetAsync(counts, 0, E_NUM * sizeof(int), stream);
  hipMemsetAsync(d_out, 0, (size_t)out_size * sizeof(float), stream);

  if (ws_size >= required) {
    int n8 = (E_NUM * F_DIM * H_DIM) / 8;   // 3,670,016
    k_cvt<<<dim3(2048), dim3(256), 0, stream>>>(w1, w1b, n8);
    k_cvt<<<dim3(2048), dim3(256), 0, stream>>>(w3, w3b, n8);
    k_cvt<<<dim3(2048), dim3(256), 0, stream>>>(w2, w2b, n8);
    k_gate<<<dim3(T_TOK / 4), dim3(256), 0, stream>>>(x, gatew, counts, ids, gws, xbf);
    k_ffn1_bf<<<dim3(F_DIM / 128, T_TOK / 128, E_NUM), dim3(256), 0, stream>>>(
        xbf, w1b, w3b, counts, ids, Gf);
    k_ffn2_bf<<<dim3(H_DIM / 128, T_TOK / 128, E_NUM), dim3(256), 0, stream>>>(
        Gf, w2b, counts, ids, gws, out);
  } else {
    unsigned short* G = (unsigned short*)(ws + (1ull << 20));
    k_gate<<<dim3(T_TOK / 4), dim3(256), 0, stream>>>(x, gatew, counts, ids, gws,
                                                      (unsigned short*)nullptr);
    k_ffn1_f32<<<dim3(F_DIM / 128, T_TOK / 128, E_NUM), dim3(256), 0, stream>>>(
        x, w1, w3, counts, ids, G);
    k_ffn2_f32<<<dim3(H_DIM / 128, T_TOK / 128, E_NUM), dim3(256), 0, stream>>>(
        G, w2, counts, ids, gws, out);
  }
}

// Round 5
// 583.999 us; speedup vs baseline: 1.2593x; 1.0753x over previous
//
#include <hip/hip_runtime.h>
#include <hip/hip_bf16.h>
#include <math.h>

// MixtralMoE: B=1, S=4096, H=1024, E=8, F=3584, K=2
// inputs: hidden_states, gate_w, w1, w3, w2 (all fp32); output fp32 [4096,1024]

#define T_TOK 4096
#define H_DIM 1024
#define E_NUM 8
#define F_DIM 3584

typedef short short8 __attribute__((ext_vector_type(8)));
typedef float f32x4 __attribute__((ext_vector_type(4)));

__device__ __forceinline__ unsigned short f2bf(float f) {
  union { float f; unsigned u; } v; v.f = f;
  unsigned r = v.u + 0x7FFFu + ((v.u >> 16) & 1u);   // RNE
  return (unsigned short)(r >> 16);
}
__device__ __forceinline__ unsigned pack2(float a, float b) {
  return (unsigned)f2bf(a) | ((unsigned)f2bf(b) << 16);
}

// async global->LDS, 16B/lane; LDS dest = wave-uniform base, HW adds lane*16.
__device__ __forceinline__ void gll16(const void* g, void* l) {
  __builtin_amdgcn_global_load_lds(
      (const __attribute__((address_space(1))) void*)g,
      (__attribute__((address_space(3))) void*)l, 16, 0, 0);
}

// swizzled LDS read; tile row stride 128 B; byte ^= (row&7)<<4
__device__ __forceinline__ short8 frag_ld(const unsigned short* lds, int row, int k) {
  int addr = (row * 128 + k * 2) ^ ((row & 7) << 4);
  return *(const short8*)((const char*)lds + addr);
}

// ---------------- fp32 -> bf16 bulk convert ---------------------------------
__global__ __launch_bounds__(256) void k_cvt(const float* __restrict__ src,
    unsigned short* __restrict__ dst, int n8) {
  int i = blockIdx.x * 256 + threadIdx.x;
  int stride = gridDim.x * 256;
  for (; i < n8; i += stride) {
    const float4* s = (const float4*)src + (size_t)i * 2;
    float4 a = s[0], b = s[1];
    ((uint4*)dst)[i] = make_uint4(pack2(a.x, a.y), pack2(a.z, a.w),
                                  pack2(b.x, b.y), pack2(b.z, b.w));
  }
}

// ---------------- gating + x->bf16 -------------------------------------------
__global__ __launch_bounds__(256) void k_gate(const float* __restrict__ x,
    const float* __restrict__ gatew, int* __restrict__ counts,
    int* __restrict__ ids, float* __restrict__ gws,
    unsigned short* __restrict__ xbf) {
  int lane = threadIdx.x & 63;
  int wid  = threadIdx.x >> 6;
  int t = blockIdx.x * 4 + wid;
  const float4* x4 = (const float4*)(x + (size_t)t * H_DIM);
  const float4* g4 = (const float4*)gatew;
  float4 xv[4];
#pragma unroll
  for (int i = 0; i < 4; ++i) xv[i] = x4[lane * 4 + i];

  if (xbf) {
    uint4* xr = (uint4*)(xbf + (size_t)t * H_DIM + lane * 16);
    xr[0] = make_uint4(pack2(xv[0].x, xv[0].y), pack2(xv[0].z, xv[0].w),
                       pack2(xv[1].x, xv[1].y), pack2(xv[1].z, xv[1].w));
    xr[1] = make_uint4(pack2(xv[2].x, xv[2].y), pack2(xv[2].z, xv[2].w),
                       pack2(xv[3].x, xv[3].y), pack2(xv[3].z, xv[3].w));
  }

  double acc[E_NUM];
#pragma unroll
  for (int e = 0; e < E_NUM; ++e) acc[e] = 0.0;
#pragma unroll
  for (int i = 0; i < 4; ++i) {
#pragma unroll
    for (int e = 0; e < E_NUM; ++e) {
      float4 gv = g4[e * 256 + lane * 4 + i];
      acc[e] += (double)xv[i].x * gv.x + (double)xv[i].y * gv.y
              + (double)xv[i].z * gv.z + (double)xv[i].w * gv.w;
    }
  }
#pragma unroll
  for (int e = 0; e < E_NUM; ++e) {
#pragma unroll
    for (int off = 32; off > 0; off >>= 1)
      acc[e] += __shfl_xor(acc[e], off, 64);
  }
  if (lane == 0) {
    int i0 = 0;
#pragma unroll
    for (int e = 1; e < E_NUM; ++e) if (acc[e] > acc[i0]) i0 = e;
    int i1 = (i0 == 0) ? 1 : 0;
#pragma unroll
    for (int e = 0; e < E_NUM; ++e)
      if (e != i0 && e != i1 && acc[e] > acc[i1]) i1 = e;
    double mx = acc[i0];
    double s = 0.0;
#pragma unroll
    for (int e = 0; e < E_NUM; ++e) s += exp(acc[e] - mx);
    float p0 = (float)(exp(acc[i0] - mx) / s);
    float p1 = (float)(exp(acc[i1] - mx) / s);
    int s0 = atomicAdd(&counts[i0], 1);
    ids[i0 * T_TOK + s0] = t * 2;      gws[i0 * T_TOK + s0] = p0;
    int s1 = atomicAdd(&counts[i1], 1);
    ids[i1 * T_TOK + s1] = t * 2 + 1;  gws[i1 * T_TOK + s1] = p1;
  }
}

// ============ fast path: 2-phase double-buffered MFMA GEMMs ==================
// staging: round p, wave w covers LDS bytes p*4096 + w*1024 + lane*16 (linear).
// linear slot (row r = 8 per 1KB, chunk c = lane&7) receives source chunk
// c ^ (r&7)  (rule 21: linear dest, inverse-swizzled source, swizzled read).

// ---- FFN up: G[slot] = silu(x@w1^T)*(x@w3^T); BM=128 BN=64 BK=64 -----------
__global__ __launch_bounds__(256) void k_ffn1_bf(const unsigned short* __restrict__ xbf,
    const unsigned short* __restrict__ w1b, const unsigned short* __restrict__ w3b,
    const int* __restrict__ counts, const int* __restrict__ ids,
    unsigned short* __restrict__ G) {
  int e = blockIdx.z;
  int count = counts[e];
  int row0 = blockIdx.y * 128;
  if (row0 >= count) return;
  int fcol0 = blockIdx.x * 64;

  __shared__ unsigned short As[2][128 * 64], B1s[2][64 * 64], B3s[2][64 * 64];
  __shared__ int ids_s[128];
  int t = threadIdx.x;
  if (t < 128) ids_s[t] = (row0 + t < count) ? ids[e * T_TOK + row0 + t] : 0;
  __syncthreads();

  int lane = t & 63, wid = t >> 6;
  const unsigned short* w1p = w1b + (size_t)e * (F_DIM * H_DIM);
  const unsigned short* w3p = w3b + (size_t)e * (F_DIM * H_DIM);

  int srck = ((lane & 7) ^ (lane >> 3)) * 8;
  unsigned offA[4], offB[2];
#pragma unroll
  for (int p = 0; p < 4; ++p) {
    int r = p * 32 + wid * 8 + (lane >> 3);
    offA[p] = (unsigned)(ids_s[r] >> 1) * H_DIM + srck;
  }
#pragma unroll
  for (int p = 0; p < 2; ++p) {
    int r = p * 32 + wid * 8 + (lane >> 3);
    offB[p] = (unsigned)(fcol0 + r) * H_DIM + srck;
  }
  unsigned ldst0 = wid * 1024;

  int wm = (wid >> 1) * 64, wn = (wid & 1) * 32;
  int fr_row = lane & 15, fr_k = (lane >> 4) * 8;
  f32x4 acc1[4][2] = {};
  f32x4 acc3[4][2] = {};

  auto STAGE = [&](int b, int kk) {
#pragma unroll
    for (int p = 0; p < 4; ++p)
      gll16(xbf + offA[p] + kk, (char*)As[b] + p * 4096 + ldst0);
#pragma unroll
    for (int p = 0; p < 2; ++p) {
      gll16(w1p + offB[p] + kk, (char*)B1s[b] + p * 4096 + ldst0);
      gll16(w3p + offB[p] + kk, (char*)B3s[b] + p * 4096 + ldst0);
    }
  };

  STAGE(0, 0);
  __syncthreads();

  const int NT = H_DIM / 64;  // 16
  for (int st = 0; st < NT; ++st) {
    int cur = st & 1;
    if (st + 1 < NT) STAGE(cur ^ 1, (st + 1) * 64);
#pragma unroll
    for (int ks = 0; ks < 2; ++ks) {
      short8 a[4];
#pragma unroll
      for (int m = 0; m < 4; ++m)
        a[m] = frag_ld(As[cur], wm + m * 16 + fr_row, ks * 32 + fr_k);
#pragma unroll
      for (int n = 0; n < 2; ++n) {
        short8 b1 = frag_ld(B1s[cur], wn + n * 16 + fr_row, ks * 32 + fr_k);
        short8 b3 = frag_ld(B3s[cur], wn + n * 16 + fr_row, ks * 32 + fr_k);
#pragma unroll
        for (int m = 0; m < 4; ++m) {
          acc1[m][n] = __builtin_amdgcn_mfma_f32_16x16x32_bf16(a[m], b1, acc1[m][n], 0, 0, 0);
          acc3[m][n] = __builtin_amdgcn_mfma_f32_16x16x32_bf16(a[m], b3, acc3[m][n], 0, 0, 0);
        }
      }
    }
    __syncthreads();
  }

  int crow = (lane >> 4) * 4, ccol = lane & 15;
#pragma unroll
  for (int m = 0; m < 4; ++m)
#pragma unroll
    for (int n = 0; n < 2; ++n)
#pragma unroll
      for (int j = 0; j < 4; ++j) {
        int rl = wm + m * 16 + crow + j;
        if (row0 + rl < count) {
          int id = ids_s[rl];
          int col = fcol0 + wn + n * 16 + ccol;
          float g1 = acc1[m][n][j], g3 = acc3[m][n][j];
          float g = g1 / (1.f + __expf(-g1)) * g3;
          G[(size_t)id * F_DIM + col] = f2bf(g);
        }
      }
}

// ---- FFN down: S2[slot] = p * (G[slot] @ w2^T); BM=128 BN=128 BK=64 --------
__global__ __launch_bounds__(256) void k_ffn2_bf(const unsigned short* __restrict__ G,
    const unsigned short* __restrict__ w2b, const int* __restrict__ counts,
    const int* __restrict__ ids, const float* __restrict__ gws,
    float* __restrict__ S2) {
  int e = blockIdx.z;
  int count = counts[e];
  int row0 = blockIdx.y * 128;
  if (row0 >= count) return;
  int hcol0 = blockIdx.x * 128;

  __shared__ unsigned short As[2][128 * 64], Bs[2][128 * 64];
  __shared__ int ids_s[128];
  __shared__ float gw_s[128];
  int t = threadIdx.x;
  if (t < 128) {
    int ok = (row0 + t < count);
    ids_s[t] = ok ? ids[e * T_TOK + row0 + t] : 0;
    gw_s[t]  = ok ? gws[e * T_TOK + row0 + t] : 0.f;
  }
  __syncthreads();

  int lane = t & 63, wid = t >> 6;
  const unsigned short* w2p = w2b + (size_t)e * (H_DIM * F_DIM);

  int srck = ((lane & 7) ^ (lane >> 3)) * 8;
  unsigned offA[4], offB[4];
#pragma unroll
  for (int p = 0; p < 4; ++p) {
    int r = p * 32 + wid * 8 + (lane >> 3);
    offA[p] = (unsigned)ids_s[r] * F_DIM + srck;
    offB[p] = (unsigned)(hcol0 + r) * F_DIM + srck;
  }
  unsigned ldst0 = wid * 1024;

  int wm = (wid >> 1) * 64, wn = (wid & 1) * 64;
  int fr_row = lane & 15, fr_k = (lane >> 4) * 8;
  f32x4 acc[4][4] = {};

  auto STAGE = [&](int b, int kk) {
#pragma unroll
    for (int p = 0; p < 4; ++p) {
      unsigned d = p * 4096 + ldst0;
      gll16(G   + offA[p] + kk, (char*)As[b] + d);
      gll16(w2p + offB[p] + kk, (char*)Bs[b] + d);
    }
  };

  STAGE(0, 0);
  __syncthreads();

  const int NT = F_DIM / 64;  // 56
  for (int st = 0; st < NT; ++st) {
    int cur = st & 1;
    if (st + 1 < NT) STAGE(cur ^ 1, (st + 1) * 64);
#pragma unroll
    for (int ks = 0; ks < 2; ++ks) {
      short8 a[4];
#pragma unroll
      for (int m = 0; m < 4; ++m)
        a[m] = frag_ld(As[cur], wm + m * 16 + fr_row, ks * 32 + fr_k);
#pragma unroll
      for (int n = 0; n < 4; ++n) {
        short8 b = frag_ld(Bs[cur], wn + n * 16 + fr_row, ks * 32 + fr_k);
#pragma unroll
        for (int m = 0; m < 4; ++m)
          acc[m][n] = __builtin_amdgcn_mfma_f32_16x16x32_bf16(a[m], b, acc[m][n], 0, 0, 0);
      }
    }
    __syncthreads();
  }

  int crow = (lane >> 4) * 4, ccol = lane & 15;
#pragma unroll
  for (int m = 0; m < 4; ++m)
#pragma unroll
    for (int n = 0; n < 4; ++n)
#pragma unroll
      for (int j = 0; j < 4; ++j) {
        int rl = wm + m * 16 + crow + j;
        if (row0 + rl < count) {
          S2[(size_t)ids_s[rl] * H_DIM + hcol0 + wn + n * 16 + ccol] =
              gw_s[rl] * acc[m][n][j];
        }
      }
}

// ---- combine: out[t] = S2[2t] + S2[2t+1] ------------------------------------
__global__ __launch_bounds__(256) void k_combine(const float* __restrict__ S2,
    float* __restrict__ out, int n4) {
  const float4* s4 = (const float4*)S2;
  float4* o4 = (float4*)out;
  int i = blockIdx.x * 256 + threadIdx.x;
  int stride = gridDim.x * 256;
  const int H4 = H_DIM / 4;
  for (; i < n4; i += stride) {
    int tk = i / H4, rem = i - tk * H4;
    float4 a = s4[(size_t)(2 * tk) * H4 + rem];
    float4 b = s4[(size_t)(2 * tk + 1) * H4 + rem];
    o4[i] = make_float4(a.x + b.x, a.y + b.y, a.z + b.z, a.w + b.w);
  }
}

// ============ fallback path (fp32 staging, R1 kernels) =======================
__device__ __forceinline__ void stage_cvt(unsigned short* lds,
    const float* __restrict__ src, int r, int c) {
  const float4* s4 = (const float4*)src;
  float4 v[4];
#pragma unroll
  for (int i = 0; i < 4; ++i) v[i] = s4[i];
  unsigned u[8];
#pragma unroll
  for (int i = 0; i < 4; ++i) {
    u[2*i]   = pack2(v[i].x, v[i].y);
    u[2*i+1] = pack2(v[i].z, v[i].w);
  }
  int base = r * 128 + c * 2;
  int sw = (r & 7) << 4;
  *(uint4*)((char*)lds + ((base     ) ^ sw)) = make_uint4(u[0], u[1], u[2], u[3]);
  *(uint4*)((char*)lds + ((base + 16) ^ sw)) = make_uint4(u[4], u[5], u[6], u[7]);
}
__device__ __forceinline__ void stage_raw(unsigned short* lds,
    const unsigned short* __restrict__ src, int r, int c) {
  uint4 v0 = ((const uint4*)src)[0];
  uint4 v1 = ((const uint4*)src)[1];
  int base = r * 128 + c * 2;
  int sw = (r & 7) << 4;
  *(uint4*)((char*)lds + ((base     ) ^ sw)) = v0;
  *(uint4*)((char*)lds + ((base + 16) ^ sw)) = v1;
}

__global__ __launch_bounds__(256) void k_ffn1_f32(const float* __restrict__ x,
    const float* __restrict__ w1, const float* __restrict__ w3,
    const int* __restrict__ counts, const int* __restrict__ ids,
    unsigned short* __restrict__ G) {
  int e = blockIdx.z;
  int count = counts[e];
  int row0 = blockIdx.y * 128;
  if (row0 >= count) return;
  int fcol0 = blockIdx.x * 128;
  __shared__ unsigned short As[128 * 64], B1s[128 * 64], B3s[128 * 64];
  __shared__ int ids_s[128];
  int t = threadIdx.x;
  if (t < 128) ids_s[t] = (row0 + t < count) ? ids[e * T_TOK + row0 + t] : 0;
  __syncthreads();
  const float* w1p = w1 + (size_t)e * F_DIM * H_DIM;
  const float* w3p = w3 + (size_t)e * F_DIM * H_DIM;
  int lane = t & 63, wid = t >> 6;
  int wm = (wid >> 1) * 64, wn = (wid & 1) * 64;
  int fr_row = lane & 15, fr_k = (lane >> 4) * 8;
  int sr = t >> 2, sc = (t & 3) * 16;
  f32x4 acc1[4][4] = {};
  f32x4 acc3[4][4] = {};
  for (int kk = 0; kk < H_DIM; kk += 64) {
#pragma unroll
    for (int p = 0; p < 2; ++p) {
      int r = p * 64 + sr;
      int id = ids_s[r];
      stage_cvt(As,  x   + (size_t)(id >> 1) * H_DIM   + kk + sc, r, sc);
      stage_cvt(B1s, w1p + (size_t)(fcol0 + r) * H_DIM + kk + sc, r, sc);
      stage_cvt(B3s, w3p + (size_t)(fcol0 + r) * H_DIM + kk + sc, r, sc);
    }
    __syncthreads();
#pragma unroll
    for (int ks = 0; ks < 2; ++ks) {
      short8 a[4];
#pragma unroll
      for (int m = 0; m < 4; ++m)
        a[m] = frag_ld(As, wm + m * 16 + fr_row, ks * 32 + fr_k);
#pragma unroll
      for (int n = 0; n < 4; ++n) {
        short8 b1 = frag_ld(B1s, wn + n * 16 + fr_row, ks * 32 + fr_k);
        short8 b3 = frag_ld(B3s, wn + n * 16 + fr_row, ks * 32 + fr_k);
#pragma unroll
        for (int m = 0; m < 4; ++m) {
          acc1[m][n] = __builtin_amdgcn_mfma_f32_16x16x32_bf16(a[m], b1, acc1[m][n], 0, 0, 0);
          acc3[m][n] = __builtin_amdgcn_mfma_f32_16x16x32_bf16(a[m], b3, acc3[m][n], 0, 0, 0);
        }
      }
    }
    __syncthreads();
  }
  int crow = (lane >> 4) * 4, ccol = lane & 15;
#pragma unroll
  for (int m = 0; m < 4; ++m)
#pragma unroll
    for (int n = 0; n < 4; ++n)
#pragma unroll
      for (int j = 0; j < 4; ++j) {
        int rl = wm + m * 16 + crow + j;
        if (row0 + rl < count) {
          int id = ids_s[rl];
          int col = fcol0 + wn + n * 16 + ccol;
          float g1 = acc1[m][n][j], g3 = acc3[m][n][j];
          float g = g1 / (1.f + __expf(-g1)) * g3;
          G[(size_t)id * F_DIM + col] = f2bf(g);
        }
      }
}

__global__ __launch_bounds__(256) void k_ffn2_f32(const unsigned short* __restrict__ G,
    const float* __restrict__ w2, const int* __restrict__ counts,
    const int* __restrict__ ids, const float* __restrict__ gws,
    float* __restrict__ out) {
  int e = blockIdx.z;
  int count = counts[e];
  int row0 = blockIdx.y * 128;
  if (row0 >= count) return;
  int hcol0 = blockIdx.x * 128;
  __shared__ unsigned short As[128 * 64], Bs[128 * 64];
  __shared__ int ids_s[128];
  __shared__ float gw_s[128];
  int t = threadIdx.x;
  if (t < 128) {
    int ok = (row0 + t < count);
    ids_s[t] = ok ? ids[e * T_TOK + row0 + t] : 0;
    gw_s[t]  = ok ? gws[e * T_TOK + row0 + t] : 0.f;
  }
  __syncthreads();
  const float* w2p = w2 + (size_t)e * H_DIM * F_DIM;
  int lane = t & 63, wid = t >> 6;
  int wm = (wid >> 1) * 64, wn = (wid & 1) * 64;
  int fr_row = lane & 15, fr_k = (lane >> 4) * 8;
  int sr = t >> 2, sc = (t & 3) * 16;
  f32x4 acc[4][4] = {};
  for (int kk = 0; kk < F_DIM; kk += 64) {
#pragma unroll
    for (int p = 0; p < 2; ++p) {
      int r = p * 64 + sr;
      stage_raw(As, G + (size_t)ids_s[r] * F_DIM + kk + sc, r, sc);
      stage_cvt(Bs, w2p + (size_t)(hcol0 + r) * F_DIM + kk + sc, r, sc);
    }
    __syncthreads();
#pragma unroll
    for (int ks = 0; ks < 2; ++ks) {
      short8 a[4];
#pragma unroll
      for (int m = 0; m < 4; ++m)
        a[m] = frag_ld(As, wm + m * 16 + fr_row, ks * 32 + fr_k);
#pragma unroll
      for (int n = 0; n < 4; ++n) {
        short8 b = frag_ld(Bs, wn + n * 16 + fr_row, ks * 32 + fr_k);
#pragma unroll
        for (int m = 0; m < 4; ++m)
          acc[m][n] = __builtin_amdgcn_mfma_f32_16x16x32_bf16(a[m], b, acc[m][n], 0, 0, 0);
      }
    }
    __syncthreads();
  }
  int crow = (lane >> 4) * 4, ccol = lane & 15;
#pragma unroll
  for (int m = 0; m < 4; ++m)
#pragma unroll
    for (int n = 0; n < 4; ++n)
#pragma unroll
      for (int j = 0; j < 4; ++j) {
        int rl = wm + m * 16 + crow + j;
        if (row0 + rl < count) {
          int tok = ids_s[rl] >> 1;
          atomicAdd(&out[(size_t)tok * H_DIM + hcol0 + wn + n * 16 + ccol],
                    gw_s[rl] * acc[m][n][j]);
        }
      }
}

// ---------------- launch -----------------------------------------------------
extern "C" void kernel_launch(void* const* d_in, const int* in_sizes, int n_in,
                              void* d_out, int out_size, void* d_ws, size_t ws_size,
                              hipStream_t stream) {
  const float* x     = (const float*)d_in[0];
  const float* gatew = (const float*)d_in[1];
  const float* w1    = (const float*)d_in[2];
  const float* w3    = (const float*)d_in[3];
  const float* w2    = (const float*)d_in[4];
  float* out = (float*)d_out;

  char* ws = (char*)d_ws;
  int*   counts = (int*)ws;
  int*   ids    = (int*)(ws + 4096);
  float* gws    = (float*)(ws + 4096 + E_NUM * T_TOK * 4);

  const size_t WBYTES = (size_t)E_NUM * F_DIM * H_DIM * 2;  // 58,720,256
  unsigned short* xbf = (unsigned short*)(ws + (1ull << 20));
  unsigned short* w1b = (unsigned short*)(ws + (16ull << 20));
  unsigned short* w3b = (unsigned short*)(ws + (16ull << 20) + WBYTES);
  unsigned short* w2b = (unsigned short*)(ws + (16ull << 20) + 2 * WBYTES);
  unsigned short* Gf  = (unsigned short*)(ws + (16ull << 20) + 3 * WBYTES);
  float* S2 = (float*)w1b;   // alias: w1b is dead once k_ffn1_bf completes
  size_t required = (16ull << 20) + 4 * WBYTES;              // ~252 MB

  hipMemsetAsync(counts, 0, E_NUM * sizeof(int), stream);

  if (ws_size >= required) {
    int n8 = (E_NUM * F_DIM * H_DIM) / 8;   // 3,670,016
    k_cvt<<<dim3(2048), dim3(256), 0, stream>>>(w1, w1b, n8);
    k_cvt<<<dim3(2048), dim3(256), 0, stream>>>(w3, w3b, n8);
    k_cvt<<<dim3(2048), dim3(256), 0, stream>>>(w2, w2b, n8);
    k_gate<<<dim3(T_TOK / 4), dim3(256), 0, stream>>>(x, gatew, counts, ids, gws, xbf);
    k_ffn1_bf<<<dim3(F_DIM / 64, T_TOK / 128, E_NUM), dim3(256), 0, stream>>>(
        xbf, w1b, w3b, counts, ids, Gf);
    k_ffn2_bf<<<dim3(H_DIM / 128, T_TOK / 128, E_NUM), dim3(256), 0, stream>>>(
        Gf, w2b, counts, ids, gws, S2);
    k_combine<<<dim3(1024), dim3(256), 0, stream>>>(
        S2, out, T_TOK * H_DIM / 4);
  } else {
    hipMemsetAsync(d_out, 0, (size_t)out_size * sizeof(float), stream);
    unsigned short* G = (unsigned short*)(ws + (1ull << 20));
    k_gate<<<dim3(T_TOK / 4), dim3(256), 0, stream>>>(x, gatew, counts, ids, gws,
                                                      (unsigned short*)nullptr);
    k_ffn1_f32<<<dim3(F_DIM / 128, T_TOK / 128, E_NUM), dim3(256), 0, stream>>>(
        x, w1, w3, counts, ids, G);
    k_ffn2_f32<<<dim3(H_DIM / 128, T_TOK / 128, E_NUM), dim3(256), 0, stream>>>(
        G, w2, counts, ids, gws, out);
  }
}

// Round 6
// 537.966 us; speedup vs baseline: 1.3671x; 1.0856x over previous
//
#include <hip/hip_runtime.h>
#include <hip/hip_bf16.h>
#include <math.h>

// MixtralMoE: B=1, S=4096, H=1024, E=8, F=3584, K=2
// inputs: hidden_states, gate_w, w1, w3, w2 (all fp32); output fp32 [4096,1024]

#define T_TOK 4096
#define H_DIM 1024
#define E_NUM 8
#define F_DIM 3584

typedef short short8 __attribute__((ext_vector_type(8)));
typedef float f32x4 __attribute__((ext_vector_type(4)));

__device__ __forceinline__ unsigned short f2bf(float f) {
  union { float f; unsigned u; } v; v.f = f;
  unsigned r = v.u + 0x7FFFu + ((v.u >> 16) & 1u);   // RNE
  return (unsigned short)(r >> 16);
}
__device__ __forceinline__ unsigned pack2(float a, float b) {
  return (unsigned)f2bf(a) | ((unsigned)f2bf(b) << 16);
}

// async global->LDS, 16B/lane; LDS dest = wave-uniform base, HW adds lane*16.
__device__ __forceinline__ void gll16(const void* g, void* l) {
  __builtin_amdgcn_global_load_lds(
      (const __attribute__((address_space(1))) void*)g,
      (__attribute__((address_space(3))) void*)l, 16, 0, 0);
}

// swizzled LDS read; tile row stride 128 B; byte ^= (row&7)<<4
__device__ __forceinline__ short8 frag_ld(const unsigned short* lds, int row, int k) {
  int addr = (row * 128 + k * 2) ^ ((row & 7) << 4);
  return *(const short8*)((const char*)lds + addr);
}

// ---------------- fp32 -> bf16 bulk convert ---------------------------------
__global__ __launch_bounds__(256) void k_cvt(const float* __restrict__ src,
    unsigned short* __restrict__ dst, int n8) {
  int i = blockIdx.x * 256 + threadIdx.x;
  int stride = gridDim.x * 256;
  for (; i < n8; i += stride) {
    const float4* s = (const float4*)src + (size_t)i * 2;
    float4 a = s[0], b = s[1];
    ((uint4*)dst)[i] = make_uint4(pack2(a.x, a.y), pack2(a.z, a.w),
                                  pack2(b.x, b.y), pack2(b.z, b.w));
  }
}

// ---------------- gating + x->bf16 -------------------------------------------
__global__ __launch_bounds__(256) void k_gate(const float* __restrict__ x,
    const float* __restrict__ gatew, int* __restrict__ counts,
    int* __restrict__ ids, float* __restrict__ gws,
    unsigned short* __restrict__ xbf) {
  int lane = threadIdx.x & 63;
  int wid  = threadIdx.x >> 6;
  int t = blockIdx.x * 4 + wid;
  const float4* x4 = (const float4*)(x + (size_t)t * H_DIM);
  const float4* g4 = (const float4*)gatew;
  float4 xv[4];
#pragma unroll
  for (int i = 0; i < 4; ++i) xv[i] = x4[lane * 4 + i];

  if (xbf) {
    uint4* xr = (uint4*)(xbf + (size_t)t * H_DIM + lane * 16);
    xr[0] = make_uint4(pack2(xv[0].x, xv[0].y), pack2(xv[0].z, xv[0].w),
                       pack2(xv[1].x, xv[1].y), pack2(xv[1].z, xv[1].w));
    xr[1] = make_uint4(pack2(xv[2].x, xv[2].y), pack2(xv[2].z, xv[2].w),
                       pack2(xv[3].x, xv[3].y), pack2(xv[3].z, xv[3].w));
  }

  double acc[E_NUM];
#pragma unroll
  for (int e = 0; e < E_NUM; ++e) acc[e] = 0.0;
#pragma unroll
  for (int i = 0; i < 4; ++i) {
#pragma unroll
    for (int e = 0; e < E_NUM; ++e) {
      float4 gv = g4[e * 256 + lane * 4 + i];
      acc[e] += (double)xv[i].x * gv.x + (double)xv[i].y * gv.y
              + (double)xv[i].z * gv.z + (double)xv[i].w * gv.w;
    }
  }
#pragma unroll
  for (int e = 0; e < E_NUM; ++e) {
#pragma unroll
    for (int off = 32; off > 0; off >>= 1)
      acc[e] += __shfl_xor(acc[e], off, 64);
  }
  if (lane == 0) {
    int i0 = 0;
#pragma unroll
    for (int e = 1; e < E_NUM; ++e) if (acc[e] > acc[i0]) i0 = e;
    int i1 = (i0 == 0) ? 1 : 0;
#pragma unroll
    for (int e = 0; e < E_NUM; ++e)
      if (e != i0 && e != i1 && acc[e] > acc[i1]) i1 = e;
    double mx = acc[i0];
    double s = 0.0;
#pragma unroll
    for (int e = 0; e < E_NUM; ++e) s += exp(acc[e] - mx);
    float p0 = (float)(exp(acc[i0] - mx) / s);
    float p1 = (float)(exp(acc[i1] - mx) / s);
    int s0 = atomicAdd(&counts[i0], 1);
    ids[i0 * T_TOK + s0] = t * 2;      gws[i0 * T_TOK + s0] = p0;
    int s1 = atomicAdd(&counts[i1], 1);
    ids[i1 * T_TOK + s1] = t * 2 + 1;  gws[i1 * T_TOK + s1] = p1;
  }
}

// ============ fast path: counted-vmcnt double-buffered MFMA GEMMs ============
// staging: round p, wave w covers LDS bytes p*4096 + w*1024 + lane*16 (linear).
// linear slot (row r, chunk c = lane&7) receives source chunk c ^ (r&7)
// (rule 21: linear dest, inverse-swizzled source, swizzled read).
// Pipeline (T4): each wave issues exactly 8 global_load_lds per K-tile;
// after issuing tile t+1's 8, `s_waitcnt vmcnt(8)` retires tile t's 8 while
// t+1's stay in flight across the raw s_barriers (no __syncthreads drain).

// ---- FFN up: G[slot] = silu(x@w1^T)*(x@w3^T); BM=128 BN=64 BK=64 -----------
__global__ __launch_bounds__(256) void k_ffn1_bf(const unsigned short* __restrict__ xbf,
    const unsigned short* __restrict__ w1b, const unsigned short* __restrict__ w3b,
    const int* __restrict__ counts, const int* __restrict__ ids,
    unsigned short* __restrict__ G) {
  int e = blockIdx.z;
  int count = counts[e];
  int row0 = blockIdx.y * 128;
  if (row0 >= count) return;
  int fcol0 = blockIdx.x * 64;

  __shared__ unsigned short As[2][128 * 64], B1s[2][64 * 64], B3s[2][64 * 64];
  __shared__ int ids_s[128];
  int t = threadIdx.x;
  if (t < 128) ids_s[t] = (row0 + t < count) ? ids[e * T_TOK + row0 + t] : 0;
  __syncthreads();

  int lane = t & 63, wid = t >> 6;
  const unsigned short* w1p = w1b + (size_t)e * (F_DIM * H_DIM);
  const unsigned short* w3p = w3b + (size_t)e * (F_DIM * H_DIM);

  int srck = ((lane & 7) ^ (lane >> 3)) * 8;
  unsigned offA[4], offB[2];
#pragma unroll
  for (int p = 0; p < 4; ++p) {
    int r = p * 32 + wid * 8 + (lane >> 3);
    offA[p] = (unsigned)(ids_s[r] >> 1) * H_DIM + srck;
  }
#pragma unroll
  for (int p = 0; p < 2; ++p) {
    int r = p * 32 + wid * 8 + (lane >> 3);
    offB[p] = (unsigned)(fcol0 + r) * H_DIM + srck;
  }
  unsigned ldst0 = wid * 1024;

  int wm = (wid >> 1) * 64, wn = (wid & 1) * 32;
  int fr_row = lane & 15, fr_k = (lane >> 4) * 8;
  f32x4 acc1[4][2] = {};
  f32x4 acc3[4][2] = {};

  auto STAGE = [&](int b, int kk) {   // 8 gll16 per wave
#pragma unroll
    for (int p = 0; p < 4; ++p)
      gll16(xbf + offA[p] + kk, (char*)As[b] + p * 4096 + ldst0);
#pragma unroll
    for (int p = 0; p < 2; ++p) {
      gll16(w1p + offB[p] + kk, (char*)B1s[b] + p * 4096 + ldst0);
      gll16(w3p + offB[p] + kk, (char*)B3s[b] + p * 4096 + ldst0);
    }
  };

  STAGE(0, 0);

  const int NT = H_DIM / 64;  // 16
  for (int st = 0; st < NT; ++st) {
    int cur = st & 1;
    if (st + 1 < NT) {
      STAGE(cur ^ 1, (st + 1) * 64);
      asm volatile("s_waitcnt vmcnt(8)" ::: "memory");   // tile st landed
    } else {
      asm volatile("s_waitcnt vmcnt(0)" ::: "memory");
    }
    __builtin_amdgcn_s_barrier();
#pragma unroll
    for (int ks = 0; ks < 2; ++ks) {
      short8 a[4];
#pragma unroll
      for (int m = 0; m < 4; ++m)
        a[m] = frag_ld(As[cur], wm + m * 16 + fr_row, ks * 32 + fr_k);
#pragma unroll
      for (int n = 0; n < 2; ++n) {
        short8 b1 = frag_ld(B1s[cur], wn + n * 16 + fr_row, ks * 32 + fr_k);
        short8 b3 = frag_ld(B3s[cur], wn + n * 16 + fr_row, ks * 32 + fr_k);
#pragma unroll
        for (int m = 0; m < 4; ++m) {
          acc1[m][n] = __builtin_amdgcn_mfma_f32_16x16x32_bf16(a[m], b1, acc1[m][n], 0, 0, 0);
          acc3[m][n] = __builtin_amdgcn_mfma_f32_16x16x32_bf16(a[m], b3, acc3[m][n], 0, 0, 0);
        }
      }
    }
    __builtin_amdgcn_s_barrier();   // readers done before next STAGE overwrites
  }

  int crow = (lane >> 4) * 4, ccol = lane & 15;
#pragma unroll
  for (int m = 0; m < 4; ++m)
#pragma unroll
    for (int n = 0; n < 2; ++n)
#pragma unroll
      for (int j = 0; j < 4; ++j) {
        int rl = wm + m * 16 + crow + j;
        if (row0 + rl < count) {
          int id = ids_s[rl];
          int col = fcol0 + wn + n * 16 + ccol;
          float g1 = acc1[m][n][j], g3 = acc3[m][n][j];
          float g = g1 / (1.f + __expf(-g1)) * g3;
          G[(size_t)id * F_DIM + col] = f2bf(g);
        }
      }
}

// ---- FFN down: S2[slot] = p * (G[slot] @ w2^T); BM=128 BN=128 BK=64 --------
__global__ __launch_bounds__(256) void k_ffn2_bf(const unsigned short* __restrict__ G,
    const unsigned short* __restrict__ w2b, const int* __restrict__ counts,
    const int* __restrict__ ids, const float* __restrict__ gws,
    float* __restrict__ S2) {
  int e = blockIdx.z;
  int count = counts[e];
  int row0 = blockIdx.y * 128;
  if (row0 >= count) return;
  int hcol0 = blockIdx.x * 128;

  __shared__ unsigned short As[2][128 * 64], Bs[2][128 * 64];
  __shared__ int ids_s[128];
  __shared__ float gw_s[128];
  int t = threadIdx.x;
  if (t < 128) {
    int ok = (row0 + t < count);
    ids_s[t] = ok ? ids[e * T_TOK + row0 + t] : 0;
    gw_s[t]  = ok ? gws[e * T_TOK + row0 + t] : 0.f;
  }
  __syncthreads();

  int lane = t & 63, wid = t >> 6;
  const unsigned short* w2p = w2b + (size_t)e * (H_DIM * F_DIM);

  int srck = ((lane & 7) ^ (lane >> 3)) * 8;
  unsigned offA[4], offB[4];
#pragma unroll
  for (int p = 0; p < 4; ++p) {
    int r = p * 32 + wid * 8 + (lane >> 3);
    offA[p] = (unsigned)ids_s[r] * F_DIM + srck;
    offB[p] = (unsigned)(hcol0 + r) * F_DIM + srck;
  }
  unsigned ldst0 = wid * 1024;

  int wm = (wid >> 1) * 64, wn = (wid & 1) * 64;
  int fr_row = lane & 15, fr_k = (lane >> 4) * 8;
  f32x4 acc[4][4] = {};

  auto STAGE = [&](int b, int kk) {   // 8 gll16 per wave
#pragma unroll
    for (int p = 0; p < 4; ++p) {
      unsigned d = p * 4096 + ldst0;
      gll16(G   + offA[p] + kk, (char*)As[b] + d);
      gll16(w2p + offB[p] + kk, (char*)Bs[b] + d);
    }
  };

  STAGE(0, 0);

  const int NT = F_DIM / 64;  // 56
  for (int st = 0; st < NT; ++st) {
    int cur = st & 1;
    if (st + 1 < NT) {
      STAGE(cur ^ 1, (st + 1) * 64);
      asm volatile("s_waitcnt vmcnt(8)" ::: "memory");
    } else {
      asm volatile("s_waitcnt vmcnt(0)" ::: "memory");
    }
    __builtin_amdgcn_s_barrier();
#pragma unroll
    for (int ks = 0; ks < 2; ++ks) {
      short8 a[4];
#pragma unroll
      for (int m = 0; m < 4; ++m)
        a[m] = frag_ld(As[cur], wm + m * 16 + fr_row, ks * 32 + fr_k);
#pragma unroll
      for (int n = 0; n < 4; ++n) {
        short8 b = frag_ld(Bs[cur], wn + n * 16 + fr_row, ks * 32 + fr_k);
#pragma unroll
        for (int m = 0; m < 4; ++m)
          acc[m][n] = __builtin_amdgcn_mfma_f32_16x16x32_bf16(a[m], b, acc[m][n], 0, 0, 0);
      }
    }
    __builtin_amdgcn_s_barrier();
  }

  int crow = (lane >> 4) * 4, ccol = lane & 15;
#pragma unroll
  for (int m = 0; m < 4; ++m)
#pragma unroll
    for (int n = 0; n < 4; ++n)
#pragma unroll
      for (int j = 0; j < 4; ++j) {
        int rl = wm + m * 16 + crow + j;
        if (row0 + rl < count) {
          S2[(size_t)ids_s[rl] * H_DIM + hcol0 + wn + n * 16 + ccol] =
              gw_s[rl] * acc[m][n][j];
        }
      }
}

// ---- combine: out[t] = S2[2t] + S2[2t+1] ------------------------------------
__global__ __launch_bounds__(256) void k_combine(const float* __restrict__ S2,
    float* __restrict__ out, int n4) {
  const float4* s4 = (const float4*)S2;
  float4* o4 = (float4*)out;
  int i = blockIdx.x * 256 + threadIdx.x;
  int stride = gridDim.x * 256;
  const int H4 = H_DIM / 4;
  for (; i < n4; i += stride) {
    int tk = i / H4, rem = i - tk * H4;
    float4 a = s4[(size_t)(2 * tk) * H4 + rem];
    float4 b = s4[(size_t)(2 * tk + 1) * H4 + rem];
    o4[i] = make_float4(a.x + b.x, a.y + b.y, a.z + b.z, a.w + b.w);
  }
}

// ============ fallback path (fp32 staging, R1 kernels) =======================
__device__ __forceinline__ void stage_cvt(unsigned short* lds,
    const float* __restrict__ src, int r, int c) {
  const float4* s4 = (const float4*)src;
  float4 v[4];
#pragma unroll
  for (int i = 0; i < 4; ++i) v[i] = s4[i];
  unsigned u[8];
#pragma unroll
  for (int i = 0; i < 4; ++i) {
    u[2*i]   = pack2(v[i].x, v[i].y);
    u[2*i+1] = pack2(v[i].z, v[i].w);
  }
  int base = r * 128 + c * 2;
  int sw = (r & 7) << 4;
  *(uint4*)((char*)lds + ((base     ) ^ sw)) = make_uint4(u[0], u[1], u[2], u[3]);
  *(uint4*)((char*)lds + ((base + 16) ^ sw)) = make_uint4(u[4], u[5], u[6], u[7]);
}
__device__ __forceinline__ void stage_raw(unsigned short* lds,
    const unsigned short* __restrict__ src, int r, int c) {
  uint4 v0 = ((const uint4*)src)[0];
  uint4 v1 = ((const uint4*)src)[1];
  int base = r * 128 + c * 2;
  int sw = (r & 7) << 4;
  *(uint4*)((char*)lds + ((base     ) ^ sw)) = v0;
  *(uint4*)((char*)lds + ((base + 16) ^ sw)) = v1;
}

__global__ __launch_bounds__(256) void k_ffn1_f32(const float* __restrict__ x,
    const float* __restrict__ w1, const float* __restrict__ w3,
    const int* __restrict__ counts, const int* __restrict__ ids,
    unsigned short* __restrict__ G) {
  int e = blockIdx.z;
  int count = counts[e];
  int row0 = blockIdx.y * 128;
  if (row0 >= count) return;
  int fcol0 = blockIdx.x * 128;
  __shared__ unsigned short As[128 * 64], B1s[128 * 64], B3s[128 * 64];
  __shared__ int ids_s[128];
  int t = threadIdx.x;
  if (t < 128) ids_s[t] = (row0 + t < count) ? ids[e * T_TOK + row0 + t] : 0;
  __syncthreads();
  const float* w1p = w1 + (size_t)e * F_DIM * H_DIM;
  const float* w3p = w3 + (size_t)e * F_DIM * H_DIM;
  int lane = t & 63, wid = t >> 6;
  int wm = (wid >> 1) * 64, wn = (wid & 1) * 64;
  int fr_row = lane & 15, fr_k = (lane >> 4) * 8;
  int sr = t >> 2, sc = (t & 3) * 16;
  f32x4 acc1[4][4] = {};
  f32x4 acc3[4][4] = {};
  for (int kk = 0; kk < H_DIM; kk += 64) {
#pragma unroll
    for (int p = 0; p < 2; ++p) {
      int r = p * 64 + sr;
      int id = ids_s[r];
      stage_cvt(As,  x   + (size_t)(id >> 1) * H_DIM   + kk + sc, r, sc);
      stage_cvt(B1s, w1p + (size_t)(fcol0 + r) * H_DIM + kk + sc, r, sc);
      stage_cvt(B3s, w3p + (size_t)(fcol0 + r) * H_DIM + kk + sc, r, sc);
    }
    __syncthreads();
#pragma unroll
    for (int ks = 0; ks < 2; ++ks) {
      short8 a[4];
#pragma unroll
      for (int m = 0; m < 4; ++m)
        a[m] = frag_ld(As, wm + m * 16 + fr_row, ks * 32 + fr_k);
#pragma unroll
      for (int n = 0; n < 4; ++n) {
        short8 b1 = frag_ld(B1s, wn + n * 16 + fr_row, ks * 32 + fr_k);
        short8 b3 = frag_ld(B3s, wn + n * 16 + fr_row, ks * 32 + fr_k);
#pragma unroll
        for (int m = 0; m < 4; ++m) {
          acc1[m][n] = __builtin_amdgcn_mfma_f32_16x16x32_bf16(a[m], b1, acc1[m][n], 0, 0, 0);
          acc3[m][n] = __builtin_amdgcn_mfma_f32_16x16x32_bf16(a[m], b3, acc3[m][n], 0, 0, 0);
        }
      }
    }
    __syncthreads();
  }
  int crow = (lane >> 4) * 4, ccol = lane & 15;
#pragma unroll
  for (int m = 0; m < 4; ++m)
#pragma unroll
    for (int n = 0; n < 4; ++n)
#pragma unroll
      for (int j = 0; j < 4; ++j) {
        int rl = wm + m * 16 + crow + j;
        if (row0 + rl < count) {
          int id = ids_s[rl];
          int col = fcol0 + wn + n * 16 + ccol;
          float g1 = acc1[m][n][j], g3 = acc3[m][n][j];
          float g = g1 / (1.f + __expf(-g1)) * g3;
          G[(size_t)id * F_DIM + col] = f2bf(g);
        }
      }
}

__global__ __launch_bounds__(256) void k_ffn2_f32(const unsigned short* __restrict__ G,
    const float* __restrict__ w2, const int* __restrict__ counts,
    const int* __restrict__ ids, const float* __restrict__ gws,
    float* __restrict__ out) {
  int e = blockIdx.z;
  int count = counts[e];
  int row0 = blockIdx.y * 128;
  if (row0 >= count) return;
  int hcol0 = blockIdx.x * 128;
  __shared__ unsigned short As[128 * 64], Bs[128 * 64];
  __shared__ int ids_s[128];
  __shared__ float gw_s[128];
  int t = threadIdx.x;
  if (t < 128) {
    int ok = (row0 + t < count);
    ids_s[t] = ok ? ids[e * T_TOK + row0 + t] : 0;
    gw_s[t]  = ok ? gws[e * T_TOK + row0 + t] : 0.f;
  }
  __syncthreads();
  const float* w2p = w2 + (size_t)e * H_DIM * F_DIM;
  int lane = t & 63, wid = t >> 6;
  int wm = (wid >> 1) * 64, wn = (wid & 1) * 64;
  int fr_row = lane & 15, fr_k = (lane >> 4) * 8;
  int sr = t >> 2, sc = (t & 3) * 16;
  f32x4 acc[4][4] = {};
  for (int kk = 0; kk < F_DIM; kk += 64) {
#pragma unroll
    for (int p = 0; p < 2; ++p) {
      int r = p * 64 + sr;
      stage_raw(As, G + (size_t)ids_s[r] * F_DIM + kk + sc, r, sc);
      stage_cvt(Bs, w2p + (size_t)(hcol0 + r) * F_DIM + kk + sc, r, sc);
    }
    __syncthreads();
#pragma unroll
    for (int ks = 0; ks < 2; ++ks) {
      short8 a[4];
#pragma unroll
      for (int m = 0; m < 4; ++m)
        a[m] = frag_ld(As, wm + m * 16 + fr_row, ks * 32 + fr_k);
#pragma unroll
      for (int n = 0; n < 4; ++n) {
        short8 b = frag_ld(Bs, wn + n * 16 + fr_row, ks * 32 + fr_k);
#pragma unroll
        for (int m = 0; m < 4; ++m)
          acc[m][n] = __builtin_amdgcn_mfma_f32_16x16x32_bf16(a[m], b, acc[m][n], 0, 0, 0);
      }
    }
    __syncthreads();
  }
  int crow = (lane >> 4) * 4, ccol = lane & 15;
#pragma unroll
  for (int m = 0; m < 4; ++m)
#pragma unroll
    for (int n = 0; n < 4; ++n)
#pragma unroll
      for (int j = 0; j < 4; ++j) {
        int rl = wm + m * 16 + crow + j;
        if (row0 + rl < count) {
          int tok = ids_s[rl] >> 1;
          atomicAdd(&out[(size_t)tok * H_DIM + hcol0 + wn + n * 16 + ccol],
                    gw_s[rl] * acc[m][n][j]);
        }
      }
}

// ---------------- launch -----------------------------------------------------
extern "C" void kernel_launch(void* const* d_in, const int* in_sizes, int n_in,
                              void* d_out, int out_size, void* d_ws, size_t ws_size,
                              hipStream_t stream) {
  const float* x     = (const float*)d_in[0];
  const float* gatew = (const float*)d_in[1];
  const float* w1    = (const float*)d_in[2];
  const float* w3    = (const float*)d_in[3];
  const float* w2    = (const float*)d_in[4];
  float* out = (float*)d_out;

  char* ws = (char*)d_ws;
  int*   counts = (int*)ws;
  int*   ids    = (int*)(ws + 4096);
  float* gws    = (float*)(ws + 4096 + E_NUM * T_TOK * 4);

  const size_t WBYTES = (size_t)E_NUM * F_DIM * H_DIM * 2;  // 58,720,256
  unsigned short* xbf = (unsigned short*)(ws + (1ull << 20));
  unsigned short* w1b = (unsigned short*)(ws + (16ull << 20));
  unsigned short* w3b = (unsigned short*)(ws + (16ull << 20) + WBYTES);
  unsigned short* w2b = (unsigned short*)(ws + (16ull << 20) + 2 * WBYTES);
  unsigned short* Gf  = (unsigned short*)(ws + (16ull << 20) + 3 * WBYTES);
  float* S2 = (float*)w1b;   // alias: w1b is dead once k_ffn1_bf completes
  size_t required = (16ull << 20) + 4 * WBYTES;              // ~252 MB

  hipMemsetAsync(counts, 0, E_NUM * sizeof(int), stream);

  if (ws_size >= required) {
    int n8 = (E_NUM * F_DIM * H_DIM) / 8;   // 3,670,016
    k_cvt<<<dim3(2048), dim3(256), 0, stream>>>(w1, w1b, n8);
    k_cvt<<<dim3(2048), dim3(256), 0, stream>>>(w3, w3b, n8);
    k_cvt<<<dim3(2048), dim3(256), 0, stream>>>(w2, w2b, n8);
    k_gate<<<dim3(T_TOK / 4), dim3(256), 0, stream>>>(x, gatew, counts, ids, gws, xbf);
    k_ffn1_bf<<<dim3(F_DIM / 64, T_TOK / 128, E_NUM), dim3(256), 0, stream>>>(
        xbf, w1b, w3b, counts, ids, Gf);
    k_ffn2_bf<<<dim3(H_DIM / 128, T_TOK / 128, E_NUM), dim3(256), 0, stream>>>(
        Gf, w2b, counts, ids, gws, S2);
    k_combine<<<dim3(1024), dim3(256), 0, stream>>>(
        S2, out, T_TOK * H_DIM / 4);
  } else {
    hipMemsetAsync(d_out, 0, (size_t)out_size * sizeof(float), stream);
    unsigned short* G = (unsigned short*)(ws + (1ull << 20));
    k_gate<<<dim3(T_TOK / 4), dim3(256), 0, stream>>>(x, gatew, counts, ids, gws,
                                                      (unsigned short*)nullptr);
    k_ffn1_f32<<<dim3(F_DIM / 128, T_TOK / 128, E_NUM), dim3(256), 0, stream>>>(
        x, w1, w3, counts, ids, G);
    k_ffn2_f32<<<dim3(H_DIM / 128, T_TOK / 128, E_NUM), dim3(256), 0, stream>>>(
        G, w2, counts, ids, gws, out);
  }
}